// Round 13
// baseline (323.806 us; speedup 1.0000x reference)
//
#include <hip/hip_runtime.h>
#include <hip/hip_fp16.h>

#define NN 100000
#define NE 3200000
#define F 64
#define NR 8
#define NCB 98                 // coarse buckets = ceil(NN/1024), bucket = dst>>10
#define CAPC 36864             // capacity per coarse bucket
#define CHUNKA 4000            // edges per binA block (800 blocks)
#define NTI 3125               // node tiles = NN/32
#define SLCAP 1280             // per-tile edge list capacity (mean 1024, +8 sigma)

typedef _Float16 half8 __attribute__((ext_vector_type(8)));
typedef float f32x4 __attribute__((ext_vector_type(4)));
union U4H8 { uint4 u; half8 h; };

// ---------------- init: per-coarse-bucket staging cursors -------------------
__global__ __launch_bounds__(128) void init_kernel(int* __restrict__ cursors) {
    int t = threadIdx.x;
    if (t < NCB) cursors[t] = t * CAPC;
}

// ---------------- cvt: x fp32 -> fp16 copy ----------------------------------
__global__ __launch_bounds__(256) void cvt_kernel(
    const float* __restrict__ x, __half* __restrict__ xh)
{
    size_t base = ((size_t)blockIdx.x * 256 + threadIdx.x) * 8;
    float4 a = *(const float4*)(x + base);
    float4 b = *(const float4*)(x + base + 4);
    __half2 h0 = __floats2half2_rn(a.x, a.y);
    __half2 h1 = __floats2half2_rn(a.z, a.w);
    __half2 h2 = __floats2half2_rn(b.x, b.y);
    __half2 h3 = __floats2half2_rn(b.z, b.w);
    uint4 o;
    o.x = *(unsigned*)&h0; o.y = *(unsigned*)&h1;
    o.z = *(unsigned*)&h2; o.w = *(unsigned*)&h3;
    *(uint4*)(xh + base) = o;
}

// ---------------- cvtw: {root, weight} -> fp16 TRANSPOSED wt9[s][n][k] ------
__global__ __launch_bounds__(256) void cvtw_kernel(
    const float* __restrict__ weight, const float* __restrict__ root,
    __half* __restrict__ wt9)
{
    int gid = blockIdx.x * 256 + threadIdx.x;   // 0..36863
    int s = gid >> 12;
    int rem = gid & 4095;
    int k = rem >> 6, n = rem & 63;
    const float* src = (s == 0) ? root : (weight + ((size_t)(s - 1) << 12));
    wt9[((size_t)s << 12) + (n << 6) + k] = __float2half_rn(src[(k << 6) + n]);
}

// ---------------- pass A: coarse-bin edges (4-copy LDS multi-split) ---------
// r8-proven form: u32 payload = src | dstLow10<<17 | rel<<27, packed at load.
__global__ __launch_bounds__(256) void binA_kernel(
    const int* __restrict__ esrc, const int* __restrict__ edst,
    const int* __restrict__ etyp,
    int* __restrict__ cursors, unsigned* __restrict__ stag4)
{
    __shared__ int hist[128][4];
    __shared__ int start[128];
    __shared__ int cur[128][4];
    __shared__ int gbase[NCB];
    __shared__ unsigned recs[CHUNKA];        // 16 KB packed payloads
    __shared__ unsigned char bks[CHUNKA];    // 4 KB bucket ids

    const int t = threadIdx.x;
    const int cp = t & 3;
    const int e0 = blockIdx.x * CHUNKA;

    if (t < 128) ((int4*)hist)[t] = make_int4(0, 0, 0, 0);
    __syncthreads();

    unsigned pay[4][4];
    unsigned bk4[4];
    const uint4* sv4 = (const uint4*)(esrc + e0);
    const uint4* dv4 = (const uint4*)(edst + e0);
    const uint4* rv4 = (const uint4*)(etyp + e0);
#pragma unroll
    for (int j = 0; j < 4; j++) {
        int g = t + (j << 8);
        if (g < CHUNKA / 4) {
            uint4 sv = sv4[g];
            uint4 dv = dv4[g];
            uint4 rv = rv4[g];
            unsigned b0 = dv.x >> 10, b1 = dv.y >> 10, b2 = dv.z >> 10, b3 = dv.w >> 10;
            pay[j][0] = sv.x | ((dv.x & 1023u) << 17) | (rv.x << 27);
            pay[j][1] = sv.y | ((dv.y & 1023u) << 17) | (rv.y << 27);
            pay[j][2] = sv.z | ((dv.z & 1023u) << 17) | (rv.z << 27);
            pay[j][3] = sv.w | ((dv.w & 1023u) << 17) | (rv.w << 27);
            bk4[j] = b0 | (b1 << 8) | (b2 << 16) | (b3 << 24);
            atomicAdd(&hist[b0][cp], 1);
            atomicAdd(&hist[b1][cp], 1);
            atomicAdd(&hist[b2][cp], 1);
            atomicAdd(&hist[b3][cp], 1);
        }
    }
    __syncthreads();

    int tot = 0;
    if (t < 128) {
        int4 h4 = ((int4*)hist)[t];
        tot = h4.x + h4.y + h4.z + h4.w;
        start[t] = tot;
    }
    __syncthreads();
    for (int off = 1; off < 128; off <<= 1) {
        int v = 0;
        if (t < 128 && t >= off) v = start[t - off];
        __syncthreads();
        if (t < 128) start[t] += v;
        __syncthreads();
    }
    if (t < 128) start[t] -= tot;   // inclusive -> exclusive
    __syncthreads();
    if (t < NCB) {
        int4 h4 = ((int4*)hist)[t];
        int s = start[t];
        cur[t][0] = s;
        cur[t][1] = s + h4.x;
        cur[t][2] = s + h4.x + h4.y;
        cur[t][3] = s + h4.x + h4.y + h4.z;
        gbase[t] = atomicAdd(&cursors[t], tot);
    }
    __syncthreads();

#pragma unroll
    for (int j = 0; j < 4; j++) {
        int g = t + (j << 8);
        if (g < CHUNKA / 4) {
#pragma unroll
            for (int k = 0; k < 4; k++) {
                int b = (int)((bk4[j] >> (k << 3)) & 255u);
                int slot = atomicAdd(&cur[b][cp], 1);
                recs[slot] = pay[j][k];
                bks[slot] = (unsigned char)b;
            }
        }
    }
    __syncthreads();

#pragma unroll
    for (int j = 0; j < 16; j++) {
        int i = t + (j << 8);
        if (i < CHUNKA) {
            int b = (int)bks[i];
            stag4[gbase[b] + (i - start[b])] = recs[i];
        }
    }
}

// ---------------- fused: bucket-filter + sort + fp16 gather + MFMA ----------
// Round-13 change: binB/scatter DELETED. Each tile-block filters its ~1K
// edges directly out of its 32.7K-edge coarse bucket (2 coalesced uint4
// passes over ~131 KB, L2/L3-served: 32 sibling blocks read the same bucket
// near-concurrently). Removes one full edge-touch stage + packed4 roundtrip.
// key8 = rel*32 + dstLow5 = ((p>>27)<<5) | ((p>>17)&31); subtile = (p>>22)&31.
__global__ __launch_bounds__(128, 4) void fused_kernel(
    const __half* __restrict__ xh,
    const unsigned* __restrict__ stag4,
    const int* __restrict__ cursors,
    const __half* __restrict__ wt9,     // [9][64 fout][64 k] fp16 (0 = root)
    const float* __restrict__ bias,
    float* __restrict__ out)
{
    __shared__ __align__(16) char Asb[32 * 128];   // As[node][k] fp16, swizzled, 4 KB
    __shared__ __align__(16) char Wtb[64 * 128];   // Wt[fout][k] fp16, swizzled, 8 KB
    __shared__ int kstart[257];                    // run starts; [256] = total
    __shared__ int slist[SLCAP];                   // 5 KB
    __shared__ int wsum[2];
    int* const kcur = (int*)Asb;         // overlay: dead until staging begins

    const int t = threadIdx.x;
    const int tile = blockIdx.x;
    const int lane = t & 63;
    const int wid = t >> 6;

    const int bkt  = tile >> 5;           // coarse bucket
    const unsigned sub = (unsigned)(tile & 31);
    const int bbase = bkt * CAPC;
    const int n = cursors[bkt] - bbase;   // bucket edge count (~32.7K)
    const int n4 = n >> 2;

    kstart[t] = 0; kstart[t + 128] = 0;
    __syncthreads();

#define KEY8(p) (int)((((p) >> 27) << 5) | (((p) >> 17) & 31u))
    // ---- pass 1: hist of this tile's keys, filtering the bucket ----
    {
        const uint4* s4 = (const uint4*)(stag4 + bbase);
        for (int g = t; g < n4; g += 128) {
            uint4 p = s4[g];
            if (((p.x >> 22) & 31u) == sub) atomicAdd(&kstart[KEY8(p.x)], 1);
            if (((p.y >> 22) & 31u) == sub) atomicAdd(&kstart[KEY8(p.y)], 1);
            if (((p.z >> 22) & 31u) == sub) atomicAdd(&kstart[KEY8(p.z)], 1);
            if (((p.w >> 22) & 31u) == sub) atomicAdd(&kstart[KEY8(p.w)], 1);
        }
        for (int i = (n4 << 2) + t; i < n; i += 128) {
            unsigned p = stag4[bbase + i];
            if (((p >> 22) & 31u) == sub) atomicAdd(&kstart[KEY8(p)], 1);
        }
    }
    __syncthreads();

    // ---- exclusive scan of 256 counts: 2 keys/thread, wave shfl scan ----
    const int a0 = kstart[2 * t], a1 = kstart[2 * t + 1];
    int v = a0 + a1;
#pragma unroll
    for (int off = 1; off < 64; off <<= 1) {
        int u = __shfl_up(v, off);
        if (lane >= off) v += u;
    }
    if (lane == 63) wsum[wid] = v;
    __syncthreads();                       // orders kstart reads vs writes below
    const int wo = wid ? wsum[0] : 0;
    const int incl = wo + v;
    const int ebase = incl - a0 - a1;
    kstart[2 * t]     = ebase;
    kstart[2 * t + 1] = ebase + a0;
    kcur[2 * t]       = ebase;
    kcur[2 * t + 1]   = ebase + a0;
    if (t == 127) kstart[256] = incl;      // total filtered edge count
    __syncthreads();

    // ---- pass 2: re-read bucket, scatter matches into per-key slist runs ----
    {
        const uint4* s4 = (const uint4*)(stag4 + bbase);
        for (int g = t; g < n4; g += 128) {
            uint4 p = s4[g];
#define PUTE(P) if ((((P) >> 22) & 31u) == sub) { \
            int slot = atomicAdd(&kcur[KEY8(P)], 1); \
            if (slot < SLCAP) slist[slot] = (int)((P) & 0x1FFFFu); }
            PUTE(p.x) PUTE(p.y) PUTE(p.z) PUTE(p.w)
        }
        for (int i = (n4 << 2) + t; i < n; i += 128) {
            unsigned p = stag4[bbase + i];
            PUTE(p)
#undef PUTE
        }
    }
    __syncthreads();   // sort frozen; kcur (Asb) dead
#undef KEY8

    // ---- per-seg: stage Wt -> gather As (wave-private fp16) -> MFMA --------
    const int node0 = tile * 32;
    const int w16 = wid << 4;             // wave's 16-node slice
    const int sn  = w16 + (lane >> 2);    // gather: node within tile 0..31
    const int sq  = lane & 3;             // gather: k-eighth 0..3
    const int kb  = sq << 3;              // halfs [kb,kb+8) and [32+kb,...)
    const unsigned snswz = (unsigned)((sn & 7) << 4);
    char* const awp = Asb + sn * 128;

    // MFMA fragment indices
    const int ml = lane & 15;             // 16-dim: node (A) / fout (B,D)
    const int kg = lane >> 4;             // k-group 0..3
    const int arow = w16 + ml;            // A row = node within tile
    const unsigned aswz = (unsigned)((arow & 7) << 4);
    const unsigned kb0 = (unsigned)(kg << 4);   // kbyte within 64B k-half

    f32x4 acc[4];
#pragma unroll
    for (int nt = 0; nt < 4; nt++)
#pragma unroll
        for (int i = 0; i < 4; i++) acc[nt][i] = 0.f;

    for (int seg = 0; seg < 9; seg++) {
        if (seg) __syncthreads();          // all waves done reading Wtb(seg-1)

        // stage Wt(seg) -> LDS with XOR swizzle (coalesced fp16 source)
        {
            const uint4* __restrict__ wsrc = (const uint4*)(wt9 + ((size_t)seg << 12));
#pragma unroll
            for (int j = 0; j < 4; j++) {
                int c = t + (j << 7);                       // 0..511
                int n2 = c >> 3;
                unsigned kbyt = (unsigned)((c & 7) << 4);
                *(uint4*)(Wtb + n2 * 128 + (kbyt ^ (unsigned)((n2 & 7) << 4))) = wsrc[c];
            }
        }

        if (seg == 0) {
            // root: copy own-row xh straight into As (fp16, swizzled)
            const __half* rowp = xh + (size_t)(node0 + sn) * F + kb;
            uint4 va = *(const uint4*)(rowp);
            uint4 vb = *(const uint4*)(rowp + 32);
            *(uint4*)(awp + (((unsigned)(sq << 4)) ^ snswz)) = va;
            *(uint4*)(awp + ((64u | (unsigned)(sq << 4)) ^ snswz)) = vb;
        } else {
            // mean-gather this wave's 16 nodes for relation seg-1 (fp16 rows)
            const int key = ((seg - 1) << 5) | sn;
            const int beg = kstart[key];
            const int end = kstart[key + 1];   // prefix property: next start
            float4 A0 = make_float4(0.f, 0.f, 0.f, 0.f);
            float4 A1 = A0, B0 = A0, B1 = A0;
            int i = beg;
            for (; i + 4 <= end; i += 4) {     // 4-edge unroll
                const __half* h0 = xh + (size_t)slist[i]     * F + kb;
                const __half* h1 = xh + (size_t)slist[i + 1] * F + kb;
                const __half* h2 = xh + (size_t)slist[i + 2] * F + kb;
                const __half* h3 = xh + (size_t)slist[i + 3] * F + kb;
                uint4 la0 = *(const uint4*)(h0);      uint4 lb0 = *(const uint4*)(h0 + 32);
                uint4 la1 = *(const uint4*)(h1);      uint4 lb1 = *(const uint4*)(h1 + 32);
                uint4 la2 = *(const uint4*)(h2);      uint4 lb2 = *(const uint4*)(h2 + 32);
                uint4 la3 = *(const uint4*)(h3);      uint4 lb3 = *(const uint4*)(h3 + 32);
#define ACC8(v, P, Q) { \
                float2 t0 = __half22float2(*(const __half2*)&(v).x); \
                float2 t1 = __half22float2(*(const __half2*)&(v).y); \
                float2 t2 = __half22float2(*(const __half2*)&(v).z); \
                float2 t3 = __half22float2(*(const __half2*)&(v).w); \
                P.x += t0.x; P.y += t0.y; P.z += t1.x; P.w += t1.y; \
                Q.x += t2.x; Q.y += t2.y; Q.z += t3.x; Q.w += t3.y; }
                ACC8(la0, A0, A1) ACC8(la1, A0, A1) ACC8(la2, A0, A1) ACC8(la3, A0, A1)
                ACC8(lb0, B0, B1) ACC8(lb1, B0, B1) ACC8(lb2, B0, B1) ACC8(lb3, B0, B1)
            }
            for (; i < end; i++) {
                const __half* h0 = xh + (size_t)slist[i] * F + kb;
                uint4 la = *(const uint4*)(h0);
                uint4 lb = *(const uint4*)(h0 + 32);
                ACC8(la, A0, A1)
                ACC8(lb, B0, B1)
            }
#undef ACC8
            const float scl = 1.0f / (float)max(end - beg, 1);
            __half2 p0 = __floats2half2_rn(A0.x * scl, A0.y * scl);
            __half2 p1 = __floats2half2_rn(A0.z * scl, A0.w * scl);
            __half2 p2 = __floats2half2_rn(A1.x * scl, A1.y * scl);
            __half2 p3 = __floats2half2_rn(A1.z * scl, A1.w * scl);
            __half2 q0 = __floats2half2_rn(B0.x * scl, B0.y * scl);
            __half2 q1 = __floats2half2_rn(B0.z * scl, B0.w * scl);
            __half2 q2 = __floats2half2_rn(B1.x * scl, B1.y * scl);
            __half2 q3 = __floats2half2_rn(B1.z * scl, B1.w * scl);
            uint4 pa, pb;
            pa.x = *(unsigned*)&p0; pa.y = *(unsigned*)&p1;
            pa.z = *(unsigned*)&p2; pa.w = *(unsigned*)&p3;
            pb.x = *(unsigned*)&q0; pb.y = *(unsigned*)&q1;
            pb.z = *(unsigned*)&q2; pb.w = *(unsigned*)&q3;
            *(uint4*)(awp + (((unsigned)(sq << 4)) ^ snswz)) = pa;
            *(uint4*)(awp + ((64u | (unsigned)(sq << 4)) ^ snswz)) = pb;
        }
        __syncthreads();                   // Wtb(seg) + As staged & visible

        // MFMA GEMM: D[16 node x 64 fout] += A[16x64] * W[64x64]
        U4H8 fa0, fa1;
        fa0.u = *(const uint4*)(Asb + arow * 128 + (kb0 ^ aswz));
        fa1.u = *(const uint4*)(Asb + arow * 128 + ((64u | kb0) ^ aswz));
#pragma unroll
        for (int nt = 0; nt < 4; nt++) {
            int wrow = (nt << 4) + ml;
            unsigned wswz = (unsigned)((wrow & 7) << 4);
            U4H8 fb0, fb1;
            fb0.u = *(const uint4*)(Wtb + wrow * 128 + (kb0 ^ wswz));
            fb1.u = *(const uint4*)(Wtb + wrow * 128 + ((64u | kb0) ^ wswz));
            acc[nt] = __builtin_amdgcn_mfma_f32_16x16x32_f16(fa0.h, fb0.h, acc[nt], 0, 0, 0);
            acc[nt] = __builtin_amdgcn_mfma_f32_16x16x32_f16(fa1.h, fb1.h, acc[nt], 0, 0, 0);
        }
    }

    // epilogue: + bias; D mapping col=lane&15, row=(lane>>4)*4+i (verified)
#pragma unroll
    for (int nt = 0; nt < 4; nt++) {
        float bb = bias[(nt << 4) + ml];
#pragma unroll
        for (int i = 0; i < 4; i++) {
            int node = node0 + w16 + (kg << 2) + i;
            out[(size_t)node * F + (nt << 4) + ml] = acc[nt][i] + bb;
        }
    }
}

extern "C" void kernel_launch(void* const* d_in, const int* in_sizes, int n_in,
                              void* d_out, int out_size, void* d_ws, size_t ws_size,
                              hipStream_t stream) {
    const float* x    = (const float*)d_in[0];
    const int*   ei   = (const int*)d_in[1];
    const int*   et   = (const int*)d_in[2];
    const float* wgt  = (const float*)d_in[3];
    const float* root = (const float*)d_in[4];
    const float* bias = (const float*)d_in[5];
    float*       out  = (float*)d_out;

    char* ws = (char*)d_ws;
    int*      cursors = (int*)ws;                                   // [128]
    unsigned* stag4   = (unsigned*)(ws + 512);                      // 14.5 MB
    __half*   xh      = (__half*)(stag4 + (size_t)NCB * CAPC);      // 12.8 MB
    __half*   wt9     = xh + (size_t)NN * F;                        // 72 KB

    init_kernel<<<1, 128, 0, stream>>>(cursors);
    cvt_kernel<<<NN * F / (256 * 8), 256, 0, stream>>>(x, xh);
    cvtw_kernel<<<144, 256, 0, stream>>>(wgt, root, wt9);
    binA_kernel<<<NE / CHUNKA, 256, 0, stream>>>(ei, ei + NE, et, cursors, stag4);
    fused_kernel<<<NTI, 128, 0, stream>>>(xh, stag4, cursors, wt9, bias, out);
}

// Round 14
// 236.376 us; speedup vs baseline: 1.3699x; 1.3699x over previous
//
#include <hip/hip_runtime.h>
#include <hip/hip_fp16.h>

#define NN 100000
#define NE 3200000
#define F 64
#define NR 8
#define NCB 98                 // coarse buckets = ceil(NN/1024), bucket = dst>>10
#define CAPC 36864             // capacity per coarse bucket
#define CHUNKA 4000            // edges per binA block (800 blocks)
#define NTI 3125               // node tiles = NN/32
#define SLCAP 1280             // per-tile edge list capacity (mean 1024, +8 sigma)
#define NKEY 8192              // per-bucket sort keys = 1024 nodes x 8 rels

typedef _Float16 half8 __attribute__((ext_vector_type(8)));
typedef float f32x4 __attribute__((ext_vector_type(4)));
union U4H8 { uint4 u; half8 h; };

// ---------------- init: per-coarse-bucket staging cursors -------------------
__global__ __launch_bounds__(128) void init_kernel(int* __restrict__ cursors) {
    int t = threadIdx.x;
    if (t < NCB) cursors[t] = t * CAPC;
}

// ---------------- cvt: x fp32 -> fp16 copy (runs AFTER binB1: xh aliases stag4)
__global__ __launch_bounds__(256) void cvt_kernel(
    const float* __restrict__ x, __half* __restrict__ xh)
{
    size_t base = ((size_t)blockIdx.x * 256 + threadIdx.x) * 8;
    float4 a = *(const float4*)(x + base);
    float4 b = *(const float4*)(x + base + 4);
    __half2 h0 = __floats2half2_rn(a.x, a.y);
    __half2 h1 = __floats2half2_rn(a.z, a.w);
    __half2 h2 = __floats2half2_rn(b.x, b.y);
    __half2 h3 = __floats2half2_rn(b.z, b.w);
    uint4 o;
    o.x = *(unsigned*)&h0; o.y = *(unsigned*)&h1;
    o.z = *(unsigned*)&h2; o.w = *(unsigned*)&h3;
    *(uint4*)(xh + base) = o;
}

// ---------------- cvtw: {root, weight} -> fp16 TRANSPOSED wt9[s][n][k] ------
__global__ __launch_bounds__(256) void cvtw_kernel(
    const float* __restrict__ weight, const float* __restrict__ root,
    __half* __restrict__ wt9)
{
    int gid = blockIdx.x * 256 + threadIdx.x;   // 0..36863
    int s = gid >> 12;
    int rem = gid & 4095;
    int k = rem >> 6, n = rem & 63;
    const float* src = (s == 0) ? root : (weight + ((size_t)(s - 1) << 12));
    wt9[((size_t)s << 12) + (n << 6) + k] = __float2half_rn(src[(k << 6) + n]);
}

// ---------------- pass A: coarse-bin edges (4-copy LDS multi-split, r8) -----
__global__ __launch_bounds__(256) void binA_kernel(
    const int* __restrict__ esrc, const int* __restrict__ edst,
    const int* __restrict__ etyp,
    int* __restrict__ cursors, unsigned* __restrict__ stag4)
{
    __shared__ int hist[128][4];
    __shared__ int start[128];
    __shared__ int cur[128][4];
    __shared__ int gbase[NCB];
    __shared__ unsigned recs[CHUNKA];        // 16 KB packed payloads
    __shared__ unsigned char bks[CHUNKA];    // 4 KB bucket ids

    const int t = threadIdx.x;
    const int cp = t & 3;
    const int e0 = blockIdx.x * CHUNKA;

    if (t < 128) ((int4*)hist)[t] = make_int4(0, 0, 0, 0);
    __syncthreads();

    unsigned pay[4][4];
    unsigned bk4[4];
    const uint4* sv4 = (const uint4*)(esrc + e0);
    const uint4* dv4 = (const uint4*)(edst + e0);
    const uint4* rv4 = (const uint4*)(etyp + e0);
#pragma unroll
    for (int j = 0; j < 4; j++) {
        int g = t + (j << 8);
        if (g < CHUNKA / 4) {
            uint4 sv = sv4[g];
            uint4 dv = dv4[g];
            uint4 rv = rv4[g];
            unsigned b0 = dv.x >> 10, b1 = dv.y >> 10, b2 = dv.z >> 10, b3 = dv.w >> 10;
            pay[j][0] = sv.x | ((dv.x & 1023u) << 17) | (rv.x << 27);
            pay[j][1] = sv.y | ((dv.y & 1023u) << 17) | (rv.y << 27);
            pay[j][2] = sv.z | ((dv.z & 1023u) << 17) | (rv.z << 27);
            pay[j][3] = sv.w | ((dv.w & 1023u) << 17) | (rv.w << 27);
            bk4[j] = b0 | (b1 << 8) | (b2 << 16) | (b3 << 24);
            atomicAdd(&hist[b0][cp], 1);
            atomicAdd(&hist[b1][cp], 1);
            atomicAdd(&hist[b2][cp], 1);
            atomicAdd(&hist[b3][cp], 1);
        }
    }
    __syncthreads();

    int tot = 0;
    if (t < 128) {
        int4 h4 = ((int4*)hist)[t];
        tot = h4.x + h4.y + h4.z + h4.w;
        start[t] = tot;
    }
    __syncthreads();
    for (int off = 1; off < 128; off <<= 1) {
        int v = 0;
        if (t < 128 && t >= off) v = start[t - off];
        __syncthreads();
        if (t < 128) start[t] += v;
        __syncthreads();
    }
    if (t < 128) start[t] -= tot;   // inclusive -> exclusive
    __syncthreads();
    if (t < NCB) {
        int4 h4 = ((int4*)hist)[t];
        int s = start[t];
        cur[t][0] = s;
        cur[t][1] = s + h4.x;
        cur[t][2] = s + h4.x + h4.y;
        cur[t][3] = s + h4.x + h4.y + h4.z;
        gbase[t] = atomicAdd(&cursors[t], tot);
    }
    __syncthreads();

#pragma unroll
    for (int j = 0; j < 4; j++) {
        int g = t + (j << 8);
        if (g < CHUNKA / 4) {
#pragma unroll
            for (int k = 0; k < 4; k++) {
                int b = (int)((bk4[j] >> (k << 3)) & 255u);
                int slot = atomicAdd(&cur[b][cp], 1);
                recs[slot] = pay[j][k];
                bks[slot] = (unsigned char)b;
            }
        }
    }
    __syncthreads();

#pragma unroll
    for (int j = 0; j < 16; j++) {
        int i = t + (j << 8);
        if (i < CHUNKA) {
            int b = (int)bks[i];
            stag4[gbase[b] + (i - start[b])] = recs[i];
        }
    }
}

// ---------------- binB1: FULL per-bucket sort to 8192 keys ------------------
// One 1024-thread block per bucket (98 blocks). key13 = dstLow10*8 + rel.
// Output: sorted src array (block OWNS its whole 131 KB region -> zero
// cross-XCD write sharing) + keystart[98][8193] cursor table. Fused's
// per-block re-sort becomes two coalesced loads.
__global__ __launch_bounds__(1024) void binB1_kernel(
    const unsigned* __restrict__ stag4, const int* __restrict__ cursors,
    unsigned* __restrict__ sorted4, int* __restrict__ keystart)
{
    __shared__ int h[NKEY];          // 32 KB: counts -> cursors
    __shared__ int wsum[16];
    const int t = threadIdx.x;
    const int lane = t & 63;
    const int wid = t >> 6;
    const int b = blockIdx.x;
    const int bbase = b * CAPC;
    const int n = cursors[b] - bbase;
    const int n4 = n >> 2;

    for (int i = t; i < NKEY; i += 1024) h[i] = 0;
    __syncthreads();

#define K13(P) (int)(((((P) >> 17) & 1023u) << 3) | ((P) >> 27))
    // pass 1: hist
    const uint4* s4 = (const uint4*)(stag4 + bbase);
    for (int g = t; g < n4; g += 1024) {
        uint4 p = s4[g];
        atomicAdd(&h[K13(p.x)], 1);
        atomicAdd(&h[K13(p.y)], 1);
        atomicAdd(&h[K13(p.z)], 1);
        atomicAdd(&h[K13(p.w)], 1);
    }
    for (int i = (n4 << 2) + t; i < n; i += 1024)
        atomicAdd(&h[K13(stag4[bbase + i])], 1);
    __syncthreads();

    // scan 8192: 8 keys/thread, wave shfl + cross-wave
    int ck[8];
    int ssum = 0;
    const int k0 = t << 3;
#pragma unroll
    for (int j = 0; j < 8; j++) { ck[j] = h[k0 + j]; ssum += ck[j]; }
    int v = ssum;
#pragma unroll
    for (int off = 1; off < 64; off <<= 1) {
        int u = __shfl_up(v, off);
        if (lane >= off) v += u;
    }
    if (lane == 63) wsum[wid] = v;
    __syncthreads();
    int wo = 0;
#pragma unroll
    for (int w = 0; w < 16; w++) if (w < wid) wo += wsum[w];
    int run = wo + v - ssum;               // exclusive base (bucket-relative)
    int* ksrow = keystart + (size_t)b * (NKEY + 1);
#pragma unroll
    for (int j = 0; j < 8; j++) {
        ksrow[k0 + j] = bbase + run;
        h[k0 + j] = run;                    // bucket-relative cursor
        run += ck[j];
    }
    if (t == 1023) ksrow[NKEY] = bbase + n;
    __syncthreads();

    // pass 2: scatter src into sorted slots (region owned by this block)
    for (int g = t; g < n4; g += 1024) {
        uint4 p = s4[g];
#define PUTS(P) { int slot = atomicAdd(&h[K13(P)], 1); \
                  sorted4[bbase + slot] = (P) & 0x1FFFFu; }
        PUTS(p.x) PUTS(p.y) PUTS(p.z) PUTS(p.w)
    }
    for (int i = (n4 << 2) + t; i < n; i += 1024) {
        unsigned p = stag4[bbase + i];
        PUTS(p)
#undef PUTS
    }
#undef K13
}

// ---------------- fused: sort-free — load sorted runs + gather + MFMA -------
// Tile t's edges are CONTIGUOUS in sorted4 (keys node-major within bucket):
// keys [sub*256, sub*256+256). Load 257 cursors + <=1280 srcs coalesced;
// gather run for (node sn, rel r) = [kstart[sn*8+r], kstart[sn*8+r+1]).
__global__ __launch_bounds__(128, 4) void fused_kernel(
    const __half* __restrict__ xh,
    const unsigned* __restrict__ sorted4,
    const int* __restrict__ keystart,
    const __half* __restrict__ wt9,     // [9][64 fout][64 k] fp16 (0 = root)
    const float* __restrict__ bias,
    float* __restrict__ out)
{
    __shared__ __align__(16) char Asb[32 * 128];   // As[node][k] fp16, swizzled, 4 KB
    __shared__ __align__(16) char Wtb[64 * 128];   // Wt[fout][k] fp16, swizzled, 8 KB
    __shared__ int kstart[257];
    __shared__ int slist[SLCAP];                   // 5 KB

    const int t = threadIdx.x;
    const int tile = blockIdx.x;
    const int lane = t & 63;
    const int wid = t >> 6;

    const int bkt = tile >> 5;
    const int sub = tile & 31;

    // load this tile's 257 cursors (coalesced)
    {
        const int* ksrow = keystart + (size_t)bkt * (NKEY + 1) + (sub << 8);
        for (int i = t; i < 257; i += 128) kstart[i] = ksrow[i];
    }
    __syncthreads();
    const int ebase0 = kstart[0];
    const int cnt = min(kstart[256] - ebase0, SLCAP);

    // load this tile's sorted src list (coalesced)
    for (int i = t; i < cnt; i += 128) slist[i] = (int)sorted4[ebase0 + i];
    __syncthreads();

    // ---- per-seg: stage Wt -> gather As (wave-private fp16) -> MFMA --------
    const int node0 = tile * 32;
    const int w16 = wid << 4;             // wave's 16-node slice
    const int sn  = w16 + (lane >> 2);    // gather: node within tile 0..31
    const int sq  = lane & 3;             // gather: k-eighth 0..3
    const int kb  = sq << 3;              // halfs [kb,kb+8) and [32+kb,...)
    const unsigned snswz = (unsigned)((sn & 7) << 4);
    char* const awp = Asb + sn * 128;

    // MFMA fragment indices
    const int ml = lane & 15;             // 16-dim: node (A) / fout (B,D)
    const int kg = lane >> 4;             // k-group 0..3
    const int arow = w16 + ml;            // A row = node within tile
    const unsigned aswz = (unsigned)((arow & 7) << 4);
    const unsigned kb0 = (unsigned)(kg << 4);   // kbyte within 64B k-half

    f32x4 acc[4];
#pragma unroll
    for (int nt = 0; nt < 4; nt++)
#pragma unroll
        for (int i = 0; i < 4; i++) acc[nt][i] = 0.f;

    for (int seg = 0; seg < 9; seg++) {
        if (seg) __syncthreads();          // all waves done reading Wtb(seg-1)

        // stage Wt(seg) -> LDS with XOR swizzle (coalesced fp16 source)
        {
            const uint4* __restrict__ wsrc = (const uint4*)(wt9 + ((size_t)seg << 12));
#pragma unroll
            for (int j = 0; j < 4; j++) {
                int c = t + (j << 7);                       // 0..511
                int n2 = c >> 3;
                unsigned kbyt = (unsigned)((c & 7) << 4);
                *(uint4*)(Wtb + n2 * 128 + (kbyt ^ (unsigned)((n2 & 7) << 4))) = wsrc[c];
            }
        }

        if (seg == 0) {
            // root: copy own-row xh straight into As (fp16, swizzled)
            const __half* rowp = xh + (size_t)(node0 + sn) * F + kb;
            uint4 va = *(const uint4*)(rowp);
            uint4 vb = *(const uint4*)(rowp + 32);
            *(uint4*)(awp + (((unsigned)(sq << 4)) ^ snswz)) = va;
            *(uint4*)(awp + ((64u | (unsigned)(sq << 4)) ^ snswz)) = vb;
        } else {
            // mean-gather this wave's 16 nodes for relation seg-1 (fp16 rows)
            int bg = kstart[(sn << 3) + seg - 1] - ebase0;
            int en = kstart[(sn << 3) + seg] - ebase0;
            if (en > cnt) en = cnt;
            if (bg > en) bg = en;
            float4 A0 = make_float4(0.f, 0.f, 0.f, 0.f);
            float4 A1 = A0, B0 = A0, B1 = A0;
            int i = bg;
            for (; i + 4 <= en; i += 4) {      // 4-edge unroll
                const __half* h0 = xh + (size_t)slist[i]     * F + kb;
                const __half* h1 = xh + (size_t)slist[i + 1] * F + kb;
                const __half* h2 = xh + (size_t)slist[i + 2] * F + kb;
                const __half* h3 = xh + (size_t)slist[i + 3] * F + kb;
                uint4 la0 = *(const uint4*)(h0);      uint4 lb0 = *(const uint4*)(h0 + 32);
                uint4 la1 = *(const uint4*)(h1);      uint4 lb1 = *(const uint4*)(h1 + 32);
                uint4 la2 = *(const uint4*)(h2);      uint4 lb2 = *(const uint4*)(h2 + 32);
                uint4 la3 = *(const uint4*)(h3);      uint4 lb3 = *(const uint4*)(h3 + 32);
#define ACC8(v, P, Q) { \
                float2 t0 = __half22float2(*(const __half2*)&(v).x); \
                float2 t1 = __half22float2(*(const __half2*)&(v).y); \
                float2 t2 = __half22float2(*(const __half2*)&(v).z); \
                float2 t3 = __half22float2(*(const __half2*)&(v).w); \
                P.x += t0.x; P.y += t0.y; P.z += t1.x; P.w += t1.y; \
                Q.x += t2.x; Q.y += t2.y; Q.z += t3.x; Q.w += t3.y; }
                ACC8(la0, A0, A1) ACC8(la1, A0, A1) ACC8(la2, A0, A1) ACC8(la3, A0, A1)
                ACC8(lb0, B0, B1) ACC8(lb1, B0, B1) ACC8(lb2, B0, B1) ACC8(lb3, B0, B1)
            }
            for (; i < en; i++) {
                const __half* h0 = xh + (size_t)slist[i] * F + kb;
                uint4 la = *(const uint4*)(h0);
                uint4 lb = *(const uint4*)(h0 + 32);
                ACC8(la, A0, A1)
                ACC8(lb, B0, B1)
            }
#undef ACC8
            const float scl = 1.0f / (float)max(en - bg, 1);
            __half2 p0 = __floats2half2_rn(A0.x * scl, A0.y * scl);
            __half2 p1 = __floats2half2_rn(A0.z * scl, A0.w * scl);
            __half2 p2 = __floats2half2_rn(A1.x * scl, A1.y * scl);
            __half2 p3 = __floats2half2_rn(A1.z * scl, A1.w * scl);
            __half2 q0 = __floats2half2_rn(B0.x * scl, B0.y * scl);
            __half2 q1 = __floats2half2_rn(B0.z * scl, B0.w * scl);
            __half2 q2 = __floats2half2_rn(B1.x * scl, B1.y * scl);
            __half2 q3 = __floats2half2_rn(B1.z * scl, B1.w * scl);
            uint4 pa, pb;
            pa.x = *(unsigned*)&p0; pa.y = *(unsigned*)&p1;
            pa.z = *(unsigned*)&p2; pa.w = *(unsigned*)&p3;
            pb.x = *(unsigned*)&q0; pb.y = *(unsigned*)&q1;
            pb.z = *(unsigned*)&q2; pb.w = *(unsigned*)&q3;
            *(uint4*)(awp + (((unsigned)(sq << 4)) ^ snswz)) = pa;
            *(uint4*)(awp + ((64u | (unsigned)(sq << 4)) ^ snswz)) = pb;
        }
        __syncthreads();                   // Wtb(seg) + As staged & visible

        // MFMA GEMM: D[16 node x 64 fout] += A[16x64] * W[64x64]
        U4H8 fa0, fa1;
        fa0.u = *(const uint4*)(Asb + arow * 128 + (kb0 ^ aswz));
        fa1.u = *(const uint4*)(Asb + arow * 128 + ((64u | kb0) ^ aswz));
#pragma unroll
        for (int nt = 0; nt < 4; nt++) {
            int wrow = (nt << 4) + ml;
            unsigned wswz = (unsigned)((wrow & 7) << 4);
            U4H8 fb0, fb1;
            fb0.u = *(const uint4*)(Wtb + wrow * 128 + (kb0 ^ wswz));
            fb1.u = *(const uint4*)(Wtb + wrow * 128 + ((64u | kb0) ^ wswz));
            acc[nt] = __builtin_amdgcn_mfma_f32_16x16x32_f16(fa0.h, fb0.h, acc[nt], 0, 0, 0);
            acc[nt] = __builtin_amdgcn_mfma_f32_16x16x32_f16(fa1.h, fb1.h, acc[nt], 0, 0, 0);
        }
    }

    // epilogue: + bias; D mapping col=lane&15, row=(lane>>4)*4+i (verified)
#pragma unroll
    for (int nt = 0; nt < 4; nt++) {
        float bb = bias[(nt << 4) + ml];
#pragma unroll
        for (int i = 0; i < 4; i++) {
            int node = node0 + w16 + (kg << 2) + i;
            out[(size_t)node * F + (nt << 4) + ml] = acc[nt][i] + bb;
        }
    }
}

extern "C" void kernel_launch(void* const* d_in, const int* in_sizes, int n_in,
                              void* d_out, int out_size, void* d_ws, size_t ws_size,
                              hipStream_t stream) {
    const float* x    = (const float*)d_in[0];
    const int*   ei   = (const int*)d_in[1];
    const int*   et   = (const int*)d_in[2];
    const float* wgt  = (const float*)d_in[3];
    const float* root = (const float*)d_in[4];
    const float* bias = (const float*)d_in[5];
    float*       out  = (float*)d_out;

    char* ws = (char*)d_ws;
    int*      cursors  = (int*)ws;                                   // [128]
    unsigned* stag4    = (unsigned*)(ws + 512);                      // 14.45 MB
    unsigned* sorted4  = stag4 + (size_t)NCB * CAPC;                 // 14.45 MB
    int*      keystart = (int*)(sorted4 + (size_t)NCB * CAPC);       // 3.21 MB
    __half*   wt9      = (__half*)(keystart + (size_t)NCB * (NKEY + 1)); // 72 KB
    __half*   xh       = (__half*)stag4;   // ALIASES stag4 (dead after binB1)

    init_kernel<<<1, 128, 0, stream>>>(cursors);
    binA_kernel<<<NE / CHUNKA, 256, 0, stream>>>(ei, ei + NE, et, cursors, stag4);
    binB1_kernel<<<NCB, 1024, 0, stream>>>(stag4, cursors, sorted4, keystart);
    cvt_kernel<<<NN * F / (256 * 8), 256, 0, stream>>>(x, xh);   // after binB1!
    cvtw_kernel<<<144, 256, 0, stream>>>(wgt, root, wt9);
    fused_kernel<<<NTI, 128, 0, stream>>>(xh, sorted4, keystart, wt9, bias, out);
}